// Round 13
// baseline (1655.627 us; speedup 1.0000x reference)
//
#include <hip/hip_runtime.h>
#include <stdint.h>

// Problem constants
#define BB   64
#define TT   512
#define HT   256
#define OO   128
#define GATES 1024   // 4*H

// R22 = R21 with the pipeline rebalanced so no stage exceeds A's floor:
// (1) role B split across 2 CUs per batch element (grid 192->256, idle
// quarter of the chip): each half owns 512 gate rows, 16 reg + 16 LDS uint4
// per thread; B step ~= poll(900) + dot(~1700) + publish < A's 3550cy.
// (2) role C issues its Ag1(t+1) sc-loads BEFORE the dot (no waitcnt) and
// drains+validates after the barrier -> prefetch RTT fully hidden.
// R21 ledger: step 5800cy = B 4800 (poll serial + full dot) | C 4100 | A 3550.
#define PREG 10
#define PLDS 4
#define PSTR 2
#define UREG (2*PREG)
#define ULDS (2*PLDS)
#define AGDEPTH 16

typedef _Float16 half_t;
typedef _Float16 half2_t __attribute__((ext_vector_type(2)));
typedef float    f32x4  __attribute__((ext_vector_type(4)));
typedef unsigned long long u64;

__device__ __forceinline__ half2_t h2_(unsigned int x) {
    return __builtin_bit_cast(half2_t, x);
}
#define WG_BARRIER() do { __builtin_amdgcn_s_waitcnt(0xC07F); \
                          __builtin_amdgcn_s_barrier(); } while (0)

__device__ __forceinline__ float fast_sig(float x) {
    return __builtin_amdgcn_rcpf(1.0f + __expf(-x));
}
__device__ __forceinline__ float fast_tanh(float x) {
    float t = __expf(2.0f * x);
    return 1.0f - 2.0f * __builtin_amdgcn_rcpf(t + 1.0f);
}

// system-coherent accesses (read the coherence point; proven R17-R21)
__device__ __forceinline__ unsigned int scload(const unsigned int* p) {
    unsigned long long a = (unsigned long long)p;
    unsigned int w;
    asm volatile("global_load_dword %0, %1, off sc0 sc1\n\ts_waitcnt vmcnt(0)"
                 : "=v"(w) : "v"(a) : "memory");
    return w;
}
__device__ __forceinline__ u64 scload64(const u64* p) {
    unsigned long long a = (unsigned long long)p;
    u64 w;
    asm volatile("global_load_dwordx2 %0, %1, off sc0 sc1\n\ts_waitcnt vmcnt(0)"
                 : "=v"(w) : "v"(a) : "memory");
    return w;
}
// batch: 4 loads in flight, ONE vmcnt wait -> 1 RTT total
__device__ __forceinline__ void scload64x4(
    const u64* p0, const u64* p1, const u64* p2, const u64* p3,
    u64& w0, u64& w1, u64& w2, u64& w3)
{
    unsigned long long a0 = (unsigned long long)p0;
    unsigned long long a1 = (unsigned long long)p1;
    unsigned long long a2 = (unsigned long long)p2;
    unsigned long long a3 = (unsigned long long)p3;
    asm volatile(
        "global_load_dwordx2 %0, %4, off sc0 sc1\n\t"
        "global_load_dwordx2 %1, %5, off sc0 sc1\n\t"
        "global_load_dwordx2 %2, %6, off sc0 sc1\n\t"
        "global_load_dwordx2 %3, %7, off sc0 sc1\n\t"
        "s_waitcnt vmcnt(0)"
        : "=v"(w0), "=v"(w1), "=v"(w2), "=v"(w3)
        : "v"(a0), "v"(a1), "v"(a2), "v"(a3) : "memory");
}
// issue WITHOUT waiting (drain later with a separate vmcnt(0))
__device__ __forceinline__ void scload64x4_issue(
    const u64* p0, const u64* p1, const u64* p2, const u64* p3,
    u64& w0, u64& w1, u64& w2, u64& w3)
{
    unsigned long long a0 = (unsigned long long)p0;
    unsigned long long a1 = (unsigned long long)p1;
    unsigned long long a2 = (unsigned long long)p2;
    unsigned long long a3 = (unsigned long long)p3;
    asm volatile(
        "global_load_dwordx2 %0, %4, off sc0 sc1\n\t"
        "global_load_dwordx2 %1, %5, off sc0 sc1\n\t"
        "global_load_dwordx2 %2, %6, off sc0 sc1\n\t"
        "global_load_dwordx2 %3, %7, off sc0 sc1"
        : "=v"(w0), "=v"(w1), "=v"(w2), "=v"(w3)
        : "v"(a0), "v"(a1), "v"(a2), "v"(a3) : "memory");
}

// 8-element fp16 dot: acc += w . h  (w, h as uint4 of packed half2)
__device__ __forceinline__ float dot8(float acc, uint4 wv, uint4 h4) {
    acc = __builtin_amdgcn_fdot2(h2_(wv.x), h2_(h4.x), acc, false);
    acc = __builtin_amdgcn_fdot2(h2_(wv.y), h2_(h4.y), acc, false);
    acc = __builtin_amdgcn_fdot2(h2_(wv.z), h2_(h4.z), acc, false);
    acc = __builtin_amdgcn_fdot2(h2_(wv.w), h2_(h4.w), acc, false);
    return acc;
}

#define PAIR_DOT(wa0, wb0, wa1, wb1, h4)                                  \
    do {                                                                   \
        a0 = __builtin_amdgcn_fdot2(h2_((wa0).x), h2_((h4).x), a0, false); \
        a0 = __builtin_amdgcn_fdot2(h2_((wa0).y), h2_((h4).y), a0, false); \
        a1 = __builtin_amdgcn_fdot2(h2_((wa0).z), h2_((h4).x), a1, false); \
        a1 = __builtin_amdgcn_fdot2(h2_((wa0).w), h2_((h4).y), a1, false); \
        a2 = __builtin_amdgcn_fdot2(h2_((wb0).x), h2_((h4).x), a2, false); \
        a2 = __builtin_amdgcn_fdot2(h2_((wb0).y), h2_((h4).y), a2, false); \
        a3 = __builtin_amdgcn_fdot2(h2_((wb0).z), h2_((h4).x), a3, false); \
        a3 = __builtin_amdgcn_fdot2(h2_((wb0).w), h2_((h4).y), a3, false); \
        a0 = __builtin_amdgcn_fdot2(h2_((wa1).x), h2_((h4).z), a0, false); \
        a0 = __builtin_amdgcn_fdot2(h2_((wa1).y), h2_((h4).w), a0, false); \
        a1 = __builtin_amdgcn_fdot2(h2_((wa1).z), h2_((h4).z), a1, false); \
        a1 = __builtin_amdgcn_fdot2(h2_((wa1).w), h2_((h4).w), a1, false); \
        a2 = __builtin_amdgcn_fdot2(h2_((wb1).x), h2_((h4).z), a2, false); \
        a2 = __builtin_amdgcn_fdot2(h2_((wb1).y), h2_((h4).w), a2, false); \
        a3 = __builtin_amdgcn_fdot2(h2_((wb1).z), h2_((h4).z), a3, false); \
        a3 = __builtin_amdgcn_fdot2(h2_((wb1).w), h2_((h4).w), a3, false); \
    } while (0)

// full dot phase over this thread's 4 gate rows x k-half (R10 verbatim)
#define DOT_PHASE()                                                        \
    do {                                                                   \
        _Pragma("unroll 2")                                                \
        for (int p = 0; p < PSTR; p++) {                                   \
            uint4 wa0 = Ws[(p * 4 + 0) * 512 + tid];                       \
            uint4 wb0 = Ws[(p * 4 + 1) * 512 + tid];                       \
            uint4 wa1 = Ws[(p * 4 + 2) * 512 + tid];                       \
            uint4 wb1 = Ws[(p * 4 + 3) * 512 + tid];                       \
            uint4 h4  = hp4[hb + PREG + PLDS + p];                         \
            PAIR_DOT(wa0, wb0, wa1, wb1, h4);                              \
        }                                                                  \
        _Pragma("unroll")                                                  \
        for (int p = 0; p < PLDS; p++) {                                   \
            uint4 wa0 = Wlh[(p * 4 + 0) * 512 + tid];                      \
            uint4 wb0 = Wlh[(p * 4 + 1) * 512 + tid];                      \
            uint4 wa1 = Wlh[(p * 4 + 2) * 512 + tid];                      \
            uint4 wb1 = Wlh[(p * 4 + 3) * 512 + tid];                      \
            uint4 h4  = hp4[hb + PREG + p];                                \
            PAIR_DOT(wa0, wb0, wa1, wb1, h4);                              \
        }                                                                  \
        _Pragma("unroll")                                                  \
        for (int p = 0; p < PREG; p++) {                                   \
            uint4 h4 = hp4[hb + p];                                        \
            PAIR_DOT(wreg[4 * p], wreg[4 * p + 1],                         \
                     wreg[4 * p + 2], wreg[4 * p + 3], h4);                \
        }                                                                  \
    } while (0)

// ---------------------------------------------------------------------------
__global__ __launch_bounds__(256) void embed_kernel(
    const int* __restrict__ actions, const float* __restrict__ emb_table,
    float* __restrict__ X, float* __restrict__ dact)
{
    int row = blockIdx.x;
    int t = row & (TT - 1);
    int id = (t == 0) ? 0 : actions[row - 1];
    X[(int64_t)row * HT + threadIdx.x] = emb_table[(int64_t)id * HT + threadIdx.x];
    if (threadIdx.x == 0) dact[row] = (float)actions[row];
}

// ---------------------------------------------------------------------------
// Repack weights: slot 0 = Whh0 (role A, R10 layout), slot 1 = Whh1 (role C,
// R10 layout), slot 2 = Wih1 (role B, SPLIT layout: half h, thread t owns
// rows 512h+2q{+0,+1} at k-half s; m 0..15 -> reg row +0, m 16..31 -> LDS
// row +1; k = 128s + 8*(m&15); idx = slot2 + (h*32+m)*512 + t).
__global__ __launch_bounds__(256) void repack_w_kernel(
    const float* __restrict__ Whh, const float* __restrict__ Wih,
    uint4* __restrict__ Wpkh)
{
    int idx = blockIdx.x * 256 + threadIdx.x;   // 0..98303
    int g   = idx & 32767;
    int l   = idx >> 15;                        // 0..2
    const float* base;
    int row, k;
    if (l < 2) {                                // R10 layout (A, C)
        int tid = g & 511;
        int ab  = (g >> 9) & 1;
        int u   = (g >> 10) & 31;
        int s = tid >> 8, q = tid & 255;
        row = 4 * q + 2 * ab;
        k   = 128 * s + 4 * u;
        base = Whh + (int64_t)l * (GATES * HT);
        // two consecutive rows packed per uint4 pair handled below
        const float4 a = *(const float4*)(base + (int64_t)row * HT + k);
        const float4 b = *(const float4*)(base + (int64_t)(row + 1) * HT + k);
        half2_t p0 = {(half_t)a.x, (half_t)a.y};
        half2_t p1 = {(half_t)a.z, (half_t)a.w};
        half2_t p2 = {(half_t)b.x, (half_t)b.y};
        half2_t p3 = {(half_t)b.z, (half_t)b.w};
        uint4 o;
        o.x = __builtin_bit_cast(unsigned int, p0);
        o.y = __builtin_bit_cast(unsigned int, p1);
        o.z = __builtin_bit_cast(unsigned int, p2);
        o.w = __builtin_bit_cast(unsigned int, p3);
        Wpkh[idx] = o;
        return;
    }
    // l == 2: split-B layout, 8 consecutive k per uint4
    {
        int t = g & 511;
        int m = (g >> 9) & 31;
        int h = g >> 14;
        int s = t >> 8, q = t & 255;
        row = 512 * h + 2 * q + (m >= 16 ? 1 : 0);
        k   = 128 * s + 8 * (m & 15);
        base = Wih + (int64_t)GATES * HT;
        const float4 a = *(const float4*)(base + (int64_t)row * HT + k);
        const float4 b = *(const float4*)(base + (int64_t)row * HT + k + 4);
        half2_t p0 = {(half_t)a.x, (half_t)a.y};
        half2_t p1 = {(half_t)a.z, (half_t)a.w};
        half2_t p2 = {(half_t)b.x, (half_t)b.y};
        half2_t p3 = {(half_t)b.z, (half_t)b.w};
        uint4 o;
        o.x = __builtin_bit_cast(unsigned int, p0);
        o.y = __builtin_bit_cast(unsigned int, p1);
        o.z = __builtin_bit_cast(unsigned int, p2);
        o.w = __builtin_bit_cast(unsigned int, p3);
        Wpkh[idx] = o;
    }
}

// ---------------------------------------------------------------------------
// Zero the h0 exchange buffer + Ag1 stamped ring + progress counters.
__global__ __launch_bounds__(256) void hxzero_kernel(
    uint4* __restrict__ HX4, u64* __restrict__ AGU,
    unsigned int* __restrict__ CCTR)
{
    int i = blockIdx.x * 256 + threadIdx.x;     // grid 8192 -> 2M
    HX4[i] = make_uint4(0u, 0u, 0u, 0u);
    if (i < AGDEPTH * 64 * 1024) AGU[i] = 0ull;
    if (i < 64) CCTR[i] = 0u;
}

// ---------------------------------------------------------------------------
// MFMA fp16 GEMM: C = act( A @ op(B) + bias1 + bias2 ), fp32 in/out.
template<bool TRANS_B, int ACT>
__global__ __launch_bounds__(256) void mfma_gemm_kernel(
    const float* __restrict__ A, const float* __restrict__ Bm,
    float* __restrict__ C,
    int K, int lda, int ldb, int ldc,
    int64_t sA, int64_t sB, int64_t sC,
    const float* __restrict__ bias1, const float* __restrict__ bias2)
{
    constexpr int BM = 128, BN = 128, BK = 32;
    constexpr int LDT = BK + 8;
    __shared__ __align__(16) half_t Asl[BM * LDT];
    __shared__ __align__(16) half_t Bsl[BN * LDT];

    const int tid  = threadIdx.x;
    const int wave = tid >> 6;
    const int lane = tid & 63;
    const int wm = (wave & 1) * 64;
    const int wn = (wave >> 1) * 64;
    const int m0 = blockIdx.y * BM;
    const int n0 = blockIdx.x * BN;
    A  += (int64_t)blockIdx.z * sA;
    Bm += (int64_t)blockIdx.z * sB;
    C  += (int64_t)blockIdx.z * sC;

    const int fm = lane & 15;
    const int qd = lane >> 4;

    f32x4 acc[4][4] = {};

    for (int k0 = 0; k0 < K; k0 += BK) {
        #pragma unroll
        for (int i = 0; i < 4; i++) {
            int idx = tid + i * 256;
            int r  = idx >> 3;
            int kq = idx & 7;
            float4 v = *(const float4*)(A + (int64_t)(m0 + r) * lda + k0 + kq * 4);
            half_t* d = &Asl[r * LDT + kq * 4];
            d[0] = (half_t)v.x; d[1] = (half_t)v.y;
            d[2] = (half_t)v.z; d[3] = (half_t)v.w;
        }
        if (TRANS_B) {
            #pragma unroll
            for (int i = 0; i < 4; i++) {
                int idx = tid + i * 256;
                int r  = idx >> 3;
                int kq = idx & 7;
                float4 v = *(const float4*)(Bm + (int64_t)(n0 + r) * ldb + k0 + kq * 4);
                half_t* d = &Bsl[r * LDT + kq * 4];
                d[0] = (half_t)v.x; d[1] = (half_t)v.y;
                d[2] = (half_t)v.z; d[3] = (half_t)v.w;
            }
        } else {
            #pragma unroll
            for (int i = 0; i < 4; i++) {
                int idx = tid + i * 256;
                int kk = idx >> 5;
                int nq = idx & 31;
                float4 v = *(const float4*)(Bm + (int64_t)(k0 + kk) * ldb + n0 + nq * 4);
                Bsl[(nq * 4 + 0) * LDT + kk] = (half_t)v.x;
                Bsl[(nq * 4 + 1) * LDT + kk] = (half_t)v.y;
                Bsl[(nq * 4 + 2) * LDT + kk] = (half_t)v.z;
                Bsl[(nq * 4 + 3) * LDT + kk] = (half_t)v.w;
            }
        }
        __syncthreads();

        typedef _Float16 f16x8 __attribute__((ext_vector_type(8)));
        f16x8 af[4], bf[4];
        #pragma unroll
        for (int t = 0; t < 4; t++)
            af[t] = *(const f16x8*)&Asl[(wm + t * 16 + fm) * LDT + qd * 8];
        #pragma unroll
        for (int t = 0; t < 4; t++)
            bf[t] = *(const f16x8*)&Bsl[(wn + t * 16 + fm) * LDT + qd * 8];
        #pragma unroll
        for (int mt = 0; mt < 4; mt++)
            #pragma unroll
            for (int nt = 0; nt < 4; nt++)
                acc[mt][nt] = __builtin_amdgcn_mfma_f32_16x16x32_f16(
                                  af[mt], bf[nt], acc[mt][nt], 0, 0, 0);
        __syncthreads();
    }

    #pragma unroll
    for (int nt = 0; nt < 4; nt++) {
        int n = n0 + wn + nt * 16 + fm;
        float bv = 0.0f;
        if (bias1) bv += bias1[n];
        if (bias2) bv += bias2[n];
        #pragma unroll
        for (int mt = 0; mt < 4; mt++) {
            #pragma unroll
            for (int r = 0; r < 4; r++) {
                int m = m0 + wm + mt * 16 + qd * 4 + r;
                float v = acc[mt][nt][r] + bv;
                if (ACT == 1) v = tanhf(v);
                C[(int64_t)m * ldc + n] = v;
            }
        }
    }
}

// ---------------------------------------------------------------------------
// Generic fp32 tiled GEMM (output chain precision).
template<bool TRANS_B, int ACT>
__global__ __launch_bounds__(256) void gemm128_kernel(
    const float* __restrict__ A, const float* __restrict__ Bm,
    float* __restrict__ C,
    int K, int lda, int ldb, int ldc,
    int64_t sA, int64_t sB, int64_t sC,
    const float* __restrict__ bias1, const float* __restrict__ bias2)
{
    constexpr int BM = 128, BN = 128, BK = 16;
    __shared__ __align__(16) float As[BK][BM + 4];
    __shared__ __align__(16) float Bs[BK][BN + 4];

    const int tid = threadIdx.x;
    const int m0 = blockIdx.y * BM;
    const int n0 = blockIdx.x * BN;
    A  += (int64_t)blockIdx.z * sA;
    Bm += (int64_t)blockIdx.z * sB;
    C  += (int64_t)blockIdx.z * sC;

    const int tm = tid & 15;
    const int tn = tid >> 4;

    float acc[8][8] = {};

    for (int k0 = 0; k0 < K; k0 += BK) {
        #pragma unroll
        for (int i = 0; i < 2; i++) {
            int idx = tid + i * 256;
            int ar = idx >> 2;
            int ak = (idx & 3) * 4;
            const float4 v = *(const float4*)(A + (int64_t)(m0 + ar) * lda + k0 + ak);
            As[ak + 0][ar] = v.x; As[ak + 1][ar] = v.y;
            As[ak + 2][ar] = v.z; As[ak + 3][ar] = v.w;
        }
        if (TRANS_B) {
            #pragma unroll
            for (int i = 0; i < 2; i++) {
                int idx = tid + i * 256;
                int br = idx >> 2;
                int bk = (idx & 3) * 4;
                const float4 v = *(const float4*)(Bm + (int64_t)(n0 + br) * ldb + k0 + bk);
                Bs[bk + 0][br] = v.x; Bs[bk + 1][br] = v.y;
                Bs[bk + 2][br] = v.z; Bs[bk + 3][br] = v.w;
            }
        } else {
            #pragma unroll
            for (int i = 0; i < 2; i++) {
                int idx = tid + i * 256;
                int bk = idx >> 5;
                int bn = (idx & 31) * 4;
                const float4 v = *(const float4*)(Bm + (int64_t)(k0 + bk) * ldb + n0 + bn);
                *(float4*)&Bs[bk][bn] = v;
            }
        }
        __syncthreads();

        #pragma unroll
        for (int k = 0; k < BK; k++) {
            float a[8], b[8];
            *(float4*)&a[0] = *(const float4*)&As[k][tm * 8];
            *(float4*)&a[4] = *(const float4*)&As[k][tm * 8 + 4];
            *(float4*)&b[0] = *(const float4*)&Bs[k][tn * 8];
            *(float4*)&b[4] = *(const float4*)&Bs[k][tn * 8 + 4];
            #pragma unroll
            for (int i = 0; i < 8; i++)
                #pragma unroll
                for (int j = 0; j < 8; j++)
                    acc[i][j] += a[i] * b[j];
        }
        __syncthreads();
    }

    float bv[8];
    #pragma unroll
    for (int j = 0; j < 8; j++) {
        int n = n0 + tn * 8 + j;
        float b = 0.0f;
        if (bias1) b += bias1[n];
        if (bias2) b += bias2[n];
        bv[j] = b;
    }
    #pragma unroll
    for (int i = 0; i < 8; i++) {
        int64_t m = m0 + tm * 8 + i;
        float o[8];
        #pragma unroll
        for (int j = 0; j < 8; j++) {
            float v = acc[i][j] + bv[j];
            if (ACT == 1) v = tanhf(v);
            o[j] = v;
        }
        *(float4*)(C + m * ldc + n0 + tn * 8)     = make_float4(o[0], o[1], o[2], o[3]);
        *(float4*)(C + m * ldc + n0 + tn * 8 + 4) = make_float4(o[4], o[5], o[6], o[7]);
    }
}

// ---------------------------------------------------------------------------
// Fused pipelined recurrence.  grid = 256 blocks: 0-63 A(b), 64-191 B(b,half),
// 192-255 C(b).  512 threads, 1 block/CU -> all co-resident.  A -> B -> C.
__global__ __launch_bounds__(512)
__attribute__((amdgpu_waves_per_eu(2, 2)))
void fused_rec_kernel(
    const float* __restrict__ Ag0,
    const uint4* __restrict__ Wpk,
    const float* __restrict__ h0l,
    const float* __restrict__ c0l,
    const float* __restrict__ bih,
    const float* __restrict__ bhh,
    float* __restrict__ cat,
    unsigned int* __restrict__ HX,     // [B*T*H] stamped h0 (write-once)
    u64* __restrict__ AGU,             // [AGDEPTH][64][1024] stamped Ag1 ring
    unsigned int* __restrict__ CCTR)   // [64] C progress counters
{
    const int bid = blockIdx.x;
    int role, b, half = 0;
    if (bid < 64)       { role = 0; b = bid; }
    else if (bid < 192) { role = 1; b = (bid - 64) & 63; half = (bid - 64) >> 6; }
    else                { role = 2; b = bid - 192; }
    const int tid = threadIdx.x;
    const int s   = tid >> 8;
    const int q   = tid & 255;

    __shared__ __align__(16) uint4          Wlh[ULDS * 2 * 512];   // 128 KB
    __shared__ __align__(16) float          gsh2[2 * GATES];       // 8 KB
    __shared__ __align__(16) float          agsh[2][GATES];        // 8 KB (role C)
    __shared__ __align__(16) unsigned short hsh[HT];               // 512 B

    const uint4* hp4 = (const uint4*)hsh;
    const int hb = 16 * s;

    if (role == 0) {
        // ---------------- Role A: layer-0 recurrence (R10) + publish ------
        const uint4* Wb = Wpk;
        uint4 wreg[2 * UREG];
        #pragma unroll
        for (int u = 0; u < UREG; u++) {
            wreg[2 * u]     = Wb[(u * 2 + 0) * 512 + tid];
            wreg[2 * u + 1] = Wb[(u * 2 + 1) * 512 + tid];
        }
        #pragma unroll
        for (int v = 0; v < ULDS; v++) {
            Wlh[(v * 2 + 0) * 512 + tid] = Wb[((UREG + v) * 2 + 0) * 512 + tid];
            Wlh[(v * 2 + 1) * 512 + tid] = Wb[((UREG + v) * 2 + 1) * 512 + tid];
        }
        const uint4* __restrict__ Ws = Wb + (UREG + ULDS) * 2 * 512;

        if (tid < HT) {
            half_t hv = (half_t)h0l[b * HT + tid];
            hsh[tid] = __builtin_bit_cast(unsigned short, hv);
        }
        float c = (tid < HT) ? c0l[b * HT + tid] : 0.0f;
        const float* AgB = Ag0 + (int64_t)b * TT * GATES;
        unsigned int* HXb = HX + (int64_t)b * TT * HT;
        __syncthreads();

        #pragma unroll 1
        for (int st = 0; st < TT; st++) {
            float4 aval = make_float4(0.f, 0.f, 0.f, 0.f);
            if (s == 0) aval = *(const float4*)(AgB + (int64_t)st * GATES + 4 * q);
            float a0 = 0.f, a1 = 0.f, a2 = 0.f, a3 = 0.f;
            DOT_PHASE();
            a0 += aval.x; a1 += aval.y; a2 += aval.z; a3 += aval.w;
            *(float4*)&gsh2[s * GATES + 4 * q] = make_float4(a0, a1, a2, a3);
            WG_BARRIER();
            if (tid < HT) {
                float gi = gsh2[tid]          + gsh2[GATES + tid];
                float gf = gsh2[HT + tid]     + gsh2[GATES + HT + tid];
                float gg = gsh2[2 * HT + tid] + gsh2[GATES + 2 * HT + tid];
                float go = gsh2[3 * HT + tid] + gsh2[GATES + 3 * HT + tid];
                c = fast_sig(gf) * c + fast_sig(gi) * fast_tanh(gg);
                float h = fast_sig(go) * fast_tanh(c);
                half_t hh = (half_t)h;
                unsigned short hb16 = __builtin_bit_cast(unsigned short, hh);
                hsh[tid] = hb16;
                atomicExch(HXb + (int64_t)st * HT + tid,
                           ((unsigned)(st + 1) << 16) | (unsigned)hb16);
            }
            WG_BARRIER();
        }
    } else if (role == 1) {
        // ---------------- Role B (split): 512 gate rows of L1 input -------
        // thread owns rows 512h+2q (reg) and 512h+2q+1 (LDS), k-half s.
        const uint4* WbB = Wpk + 2 * 32768 + (half * 32) * 512 + tid;
        uint4 wr[16];
        #pragma unroll
        for (int m = 0; m < 16; m++) wr[m] = WbB[m * 512];
        #pragma unroll
        for (int m = 0; m < 16; m++) Wlh[m * 512 + tid] = WbB[(16 + m) * 512];

        float brow = bih[GATES + 512 * half + tid] + bhh[GATES + 512 * half + tid];
        const unsigned int* HXb = HX + (int64_t)b * TT * HT;
        const uint4* wlB = Wlh + tid;
        __syncthreads();

        #pragma unroll 1
        for (int st = 0; st < TT; st++) {
            // ring back-pressure: ensure C consumed slot before reuse
            if ((st & 3) == 0 && st >= AGDEPTH && tid == 0) {
                while (scload(&CCTR[b]) < (unsigned)(st - (AGDEPTH - 4))) {}
            }
            // poll h0_t (write-once stamped words, 1 RTT when ready)
            if (tid < HT) {
                const unsigned int* src = HXb + (int64_t)st * HT + tid;
                unsigned int w = scload(src);
                while ((w >> 16) != (unsigned)(st + 1)) w = scload(src);
                hsh[tid] = (unsigned short)(w & 0xffffu);
            }
            WG_BARRIER();
            float a0 = 0.f, a1 = 0.f;
            #pragma unroll
            for (int u = 0; u < 16; u++) {
                uint4 h4 = hp4[16 * s + u];
                a0 = dot8(a0, wr[u], h4);
                a1 = dot8(a1, wlB[u * 512], h4);
            }
            gsh2[s * 512 + 2 * q]     = a0;
            gsh2[s * 512 + 2 * q + 1] = a1;
            WG_BARRIER();
            // combine + publish: all 512 threads own one row each
            {
                float v = gsh2[tid] + gsh2[512 + tid] + brow;
                u64 w = (((u64)(st + 1)) << 32) | (u64)__float_as_uint(v);
                atomicExch(AGU + (int64_t)((st & (AGDEPTH - 1)) * 64 + b) * 1024
                               + 512 * half + tid, w);
            }
            // no third barrier: next poll writes hsh (ordered by barrier #1)
        }
    } else {
        // ---------------- Role C: layer-1 recurrence ----------------------
        const uint4* Wb = Wpk + 32768;
        uint4 wreg[2 * UREG];
        #pragma unroll
        for (int u = 0; u < UREG; u++) {
            wreg[2 * u]     = Wb[(u * 2 + 0) * 512 + tid];
            wreg[2 * u + 1] = Wb[(u * 2 + 1) * 512 + tid];
        }
        #pragma unroll
        for (int v = 0; v < ULDS; v++) {
            Wlh[(v * 2 + 0) * 512 + tid] = Wb[((UREG + v) * 2 + 0) * 512 + tid];
            Wlh[(v * 2 + 1) * 512 + tid] = Wb[((UREG + v) * 2 + 1) * 512 + tid];
        }
        const uint4* __restrict__ Ws = Wb + (UREG + ULDS) * 2 * 512;

        if (tid < HT) {
            half_t hv = (half_t)h0l[BB * HT + b * HT + tid];
            hsh[tid] = __builtin_bit_cast(unsigned short, hv);
        }
        float c = (tid < HT) ? c0l[BB * HT + b * HT + tid] : 0.0f;
        __syncthreads();
        // preload Ag1(0) into agsh[0] (waves 4-7, batch-validated, blocking)
        if (tid >= 256) {
            int i = tid - 256;
            const u64* src = AGU + (int64_t)b * 1024;
            u64 w0, w1, w2, w3;
            scload64x4(src + i, src + i + 256, src + i + 512, src + i + 768,
                       w0, w1, w2, w3);
            while ((unsigned)(w0 >> 32) != 1u) w0 = scload64(src + i);
            while ((unsigned)(w1 >> 32) != 1u) w1 = scload64(src + i + 256);
            while ((unsigned)(w2 >> 32) != 1u) w2 = scload64(src + i + 512);
            while ((unsigned)(w3 >> 32) != 1u) w3 = scload64(src + i + 768);
            agsh[0][i]       = __uint_as_float((unsigned)w0);
            agsh[0][i + 256] = __uint_as_float((unsigned)w1);
            agsh[0][i + 512] = __uint_as_float((unsigned)w2);
            agsh[0][i + 768] = __uint_as_float((unsigned)w3);
        }
        WG_BARRIER();

        #pragma unroll 1
        for (int st = 0; st < TT; st++) {
            // issue Ag1(st+1) loads BEFORE the dot (drain after barrier):
            // the ~1-RTT latency hides entirely under the ~3470cy dot.
            u64 pw0 = 0, pw1 = 0, pw2 = 0, pw3 = 0;
            if (tid >= 256 && st + 1 < TT) {
                int i = tid - 256;
                int sl = (st + 1) & (AGDEPTH - 1);
                const u64* src = AGU + (int64_t)(sl * 64 + b) * 1024;
                scload64x4_issue(src + i, src + i + 256, src + i + 512,
                                 src + i + 768, pw0, pw1, pw2, pw3);
            }
            float a0 = 0.f, a1 = 0.f, a2 = 0.f, a3 = 0.f;
            DOT_PHASE();
            *(f32x4*)&gsh2[s * GATES + 4 * q] = f32x4{a0, a1, a2, a3};
            WG_BARRIER();
            if (tid < HT) {
                const float* ag = agsh[st & 1];
                float gi = gsh2[tid]          + gsh2[GATES + tid]          + ag[tid];
                float gf = gsh2[HT + tid]     + gsh2[GATES + HT + tid]     + ag[HT + tid];
                float gg = gsh2[2 * HT + tid] + gsh2[GATES + 2 * HT + tid] + ag[2 * HT + tid];
                float go = gsh2[3 * HT + tid] + gsh2[GATES + 3 * HT + tid] + ag[3 * HT + tid];
                c = fast_sig(gf) * c + fast_sig(gi) * fast_tanh(gg);
                float h = fast_sig(go) * fast_tanh(c);
                hsh[tid] = __builtin_bit_cast(unsigned short, (half_t)h);
                cat[((int64_t)b * TT + st) * (2 * HT) + tid] = h;
            } else {
                if ((st & 3) == 3 && tid == 256)
                    atomicExch(&CCTR[b], (unsigned)(st + 1));
                if (st + 1 < TT) {
                    int i = tid - 256;
                    int sl = (st + 1) & (AGDEPTH - 1);
                    unsigned expect = (unsigned)(st + 2);
                    const u64* src = AGU + (int64_t)(sl * 64 + b) * 1024;
                    asm volatile("s_waitcnt vmcnt(0)" ::: "memory");
                    while ((unsigned)(pw0 >> 32) != expect) pw0 = scload64(src + i);
                    while ((unsigned)(pw1 >> 32) != expect) pw1 = scload64(src + i + 256);
                    while ((unsigned)(pw2 >> 32) != expect) pw2 = scload64(src + i + 512);
                    while ((unsigned)(pw3 >> 32) != expect) pw3 = scload64(src + i + 768);
                    float* d = agsh[(st + 1) & 1];
                    d[i]       = __uint_as_float((unsigned)pw0);
                    d[i + 256] = __uint_as_float((unsigned)pw1);
                    d[i + 512] = __uint_as_float((unsigned)pw2);
                    d[i + 768] = __uint_as_float((unsigned)pw3);
                }
            }
            WG_BARRIER();
        }
    }
}

// ---------------------------------------------------------------------------
__global__ __launch_bounds__(256) void softmax512_kernel(float* __restrict__ S)
{
    int row = blockIdx.x * 4 + (threadIdx.x >> 6);
    int lane = threadIdx.x & 63;
    float* p = S + (int64_t)row * 512 + lane * 8;
    float4 v0 = *(float4*)p;
    float4 v1 = *(float4*)(p + 4);
    float m = fmaxf(fmaxf(fmaxf(v0.x, v0.y), fmaxf(v0.z, v0.w)),
                    fmaxf(fmaxf(v1.x, v1.y), fmaxf(v1.z, v1.w)));
    #pragma unroll
    for (int off = 32; off; off >>= 1) m = fmaxf(m, __shfl_xor(m, off));
    v0.x = __expf(v0.x - m); v0.y = __expf(v0.y - m);
    v0.z = __expf(v0.z - m); v0.w = __expf(v0.w - m);
    v1.x = __expf(v1.x - m); v1.y = __expf(v1.y - m);
    v1.z = __expf(v1.z - m); v1.w = __expf(v1.w - m);
    float s = v0.x + v0.y + v0.z + v0.w + v1.x + v1.y + v1.z + v1.w;
    #pragma unroll
    for (int off = 32; off; off >>= 1) s += __shfl_xor(s, off);
    float inv = 1.0f / s;
    v0.x *= inv; v0.y *= inv; v0.z *= inv; v0.w *= inv;
    v1.x *= inv; v1.y *= inv; v1.z *= inv; v1.w *= inv;
    *(float4*)p = v0;
    *(float4*)(p + 4) = v1;
}

__global__ __launch_bounds__(256) void values_kernel(
    const float* __restrict__ Q, const float* __restrict__ L, float* __restrict__ V)
{
    int row = blockIdx.x * 4 + (threadIdx.x >> 6);
    int lane = threadIdx.x & 63;
    float2 q = *(const float2*)(Q + (int64_t)row * OO + lane * 2);
    float2 l = *(const float2*)(L + (int64_t)row * OO + lane * 2);
    float s = q.x * l.x + q.y * l.y;
    #pragma unroll
    for (int off = 32; off; off >>= 1) s += __shfl_xor(s, off);
    if (lane == 0) V[row] = s;
}

// ---------------------------------------------------------------------------
extern "C" void kernel_launch(void* const* d_in, const int* in_sizes, int n_in,
                              void* d_out, int out_size, void* d_ws, size_t ws_size,
                              hipStream_t stream)
{
    const float* enc      = (const float*)d_in[0];
    const float* h0       = (const float*)d_in[1];
    const float* c0       = (const float*)d_in[2];
    const int*   actions  = (const int*)  d_in[3];
    const float* emb_t    = (const float*)d_in[4];
    const float* Wih      = (const float*)d_in[5];
    const float* Whh      = (const float*)d_in[6];
    const float* bih      = (const float*)d_in[7];
    const float* bhh      = (const float*)d_in[8];
    const float* W_attn   = (const float*)d_in[9];
    const float* b_attn   = (const float*)d_in[10];
    const float* W_concat = (const float*)d_in[11];
    const float* b_concat = (const float*)d_in[12];
    const float* W_out    = (const float*)d_in[13];
    const float* W_critic = (const float*)d_in[14];
    const float* b_critic = (const float*)d_in[15];
    (void)in_sizes; (void)n_in; (void)out_size; (void)ws_size;

    const int M = BB * TT;                 // 32768

    float* out    = (float*)d_out;
    float* dact   = out;
    float* logits = out + M;
    float* values = out + M + (int64_t)M * OO;

    float* ws    = (float*)d_ws;
    float* gates = ws;                       // Ag0, 128 MB
    float* xbuf  = ws + 33554432;            // emb -> (zeroed) -> HX -> dec
    float* cat   = ws + 41943040;            // [M,512]: h1 | ctx
    float* keysR = ws + 58720256;
    float* keys  = keysR;
    uint4* Wpkh  = (uint4*)keysR;            // 1.5 MB; dead before keys
    u64*   AGU   = (u64*)(ws + 59500000);    // 8 MB stamped ring (dead-keys region)
    unsigned int* CCTR = (unsigned int*)(ws + 61600000);
    unsigned int* HX   = (unsigned int*)xbuf;
    float* scores = gates;
    float* qv     = gates;
    float* dec    = xbuf;

    // 1) embedding -> xbuf, + decoder_action
    hipLaunchKernelGGL(embed_kernel, dim3(M), dim3(256), 0, stream,
                       actions, emb_t, xbuf, dact);
    // 2) repack Whh0/Whh1 (R10 layout) + Wih1 (split-B layout)
    hipLaunchKernelGGL(repack_w_kernel, dim3(384), dim3(256), 0, stream,
                       Whh, Wih, Wpkh);
    // 3) layer-0 input GEMM: gates = emb @ Wih0^T + bih0 + bhh0
    hipLaunchKernelGGL((mfma_gemm_kernel<true, 0>), dim3(8, 256, 1), dim3(256), 0, stream,
                       xbuf, Wih, gates, HT, HT, HT, GATES,
                       (int64_t)0, (int64_t)0, (int64_t)0, bih, bhh);
    // 4) zero h0-exchange buffer (emb consumed) + stamped ring + counters
    hipLaunchKernelGGL(hxzero_kernel, dim3(8192), dim3(256), 0, stream,
                       (uint4*)HX, AGU, CCTR);
    // 5) fused pipelined recurrence: L0 rec || 2x L1 input || L1 rec
    hipLaunchKernelGGL(fused_rec_kernel, dim3(256), dim3(512), 0, stream,
                       gates, Wpkh, h0, c0, bih, bhh, cat, HX, AGU, CCTR);
    // 6) keys = enc @ W_attn^T + b_attn (MFMA fp16)
    hipLaunchKernelGGL((mfma_gemm_kernel<true, 0>), dim3(2, 256, 1), dim3(256), 0, stream,
                       enc, W_attn, keys, HT, HT, HT, HT,
                       (int64_t)0, (int64_t)0, (int64_t)0, b_attn, (const float*)nullptr);
    // 7) scores[b] = out[b] @ keys[b]^T  (MFMA fp16, fp32 accumulate)
    hipLaunchKernelGGL((mfma_gemm_kernel<true, 0>), dim3(4, 4, BB), dim3(256), 0, stream,
                       cat, keys, scores, HT, 2 * HT, HT, TT,
                       (int64_t)TT * 2 * HT, (int64_t)TT * HT, (int64_t)TT * TT,
                       (const float*)nullptr, (const float*)nullptr);
    // 8) softmax
    hipLaunchKernelGGL(softmax512_kernel, dim3(M / 4), dim3(256), 0, stream, scores);
    // 9) ctx[b] = P[b] @ enc[b] -> cat[:,256:]  (MFMA fp16)
    hipLaunchKernelGGL((mfma_gemm_kernel<false, 0>), dim3(2, 4, BB), dim3(256), 0, stream,
                       scores, enc, cat + HT, TT, TT, HT, 2 * HT,
                       (int64_t)TT * TT, (int64_t)TT * HT, (int64_t)TT * 2 * HT,
                       (const float*)nullptr, (const float*)nullptr);
    // 10) dec = tanh(cat @ W_concat^T + b_concat)
    hipLaunchKernelGGL((mfma_gemm_kernel<true, 1>), dim3(2, 256, 1), dim3(256), 0, stream,
                       cat, W_concat, dec, 2 * HT, 2 * HT, 2 * HT, HT,
                       (int64_t)0, (int64_t)0, (int64_t)0, b_concat, (const float*)nullptr);
    // 11) logits = dec @ W_out^T  (fp32 — output path)
    hipLaunchKernelGGL((gemm128_kernel<true, 0>), dim3(1, 256, 1), dim3(256), 0, stream,
                       dec, W_out, logits, HT, HT, HT, OO,
                       (int64_t)0, (int64_t)0, (int64_t)0,
                       (const float*)nullptr, (const float*)nullptr);
    // 12) qv = logits @ W_critic^T + b_critic  (fp32 — output path)
    hipLaunchKernelGGL((gemm128_kernel<true, 0>), dim3(1, 256, 1), dim3(256), 0, stream,
                       logits, W_critic, qv, OO, OO, OO, OO,
                       (int64_t)0, (int64_t)0, (int64_t)0, b_critic, (const float*)nullptr);
    // 13) values
    hipLaunchKernelGGL(values_kernel, dim3(M / 4), dim3(256), 0, stream,
                       qv, logits, values);
}

// Round 14
// 1550.386 us; speedup vs baseline: 1.0679x; 1.0679x over previous
//
#include <hip/hip_runtime.h>
#include <stdint.h>

// Problem constants
#define BB   64
#define TT   512
#define HT   256
#define OO   128
#define GATES 1024   // 4*H

// R23 = R21 base (B un-split, grid 192) + atomic/vmcnt decoupling:
// Diagnosis of the ~5800cy/step plateau (R19-R22): vmcnt retires IN ORDER,
// so each stage's tail atomics (contested by the consumer's sc-poll flood)
// block the next step's first vmem wait -> rate = dot + contested drain.
// Fixes: (1) DOT_PHASE reordered REG->LDS->STREAM: tail atomics get ~2800cy
// of wait-free dot before any vmem wait; (2) B publishes from waves 4-7 so
// polling waves' vmcnt(0) never drains atomics; (3) s_sleep backoff in all
// spin loops cuts the poll flood (and thus the drain latency) itself.
#define PREG 10
#define PLDS 4
#define PSTR 2
#define UREG (2*PREG)
#define ULDS (2*PLDS)
#define AGDEPTH 16

typedef _Float16 half_t;
typedef _Float16 half2_t __attribute__((ext_vector_type(2)));
typedef float    f32x4  __attribute__((ext_vector_type(4)));
typedef unsigned long long u64;

__device__ __forceinline__ half2_t h2_(unsigned int x) {
    return __builtin_bit_cast(half2_t, x);
}
#define WG_BARRIER() do { __builtin_amdgcn_s_waitcnt(0xC07F); \
                          __builtin_amdgcn_s_barrier(); } while (0)

__device__ __forceinline__ float fast_sig(float x) {
    return __builtin_amdgcn_rcpf(1.0f + __expf(-x));
}
__device__ __forceinline__ float fast_tanh(float x) {
    float t = __expf(2.0f * x);
    return 1.0f - 2.0f * __builtin_amdgcn_rcpf(t + 1.0f);
}

// system-coherent accesses (read the coherence point; proven R17-R22)
__device__ __forceinline__ unsigned int scload(const unsigned int* p) {
    unsigned long long a = (unsigned long long)p;
    unsigned int w;
    asm volatile("global_load_dword %0, %1, off sc0 sc1\n\ts_waitcnt vmcnt(0)"
                 : "=v"(w) : "v"(a) : "memory");
    return w;
}
__device__ __forceinline__ u64 scload64(const u64* p) {
    unsigned long long a = (unsigned long long)p;
    u64 w;
    asm volatile("global_load_dwordx2 %0, %1, off sc0 sc1\n\ts_waitcnt vmcnt(0)"
                 : "=v"(w) : "v"(a) : "memory");
    return w;
}
// batch: 4 loads in flight, ONE vmcnt wait -> 1 RTT total
__device__ __forceinline__ void scload64x4(
    const u64* p0, const u64* p1, const u64* p2, const u64* p3,
    u64& w0, u64& w1, u64& w2, u64& w3)
{
    unsigned long long a0 = (unsigned long long)p0;
    unsigned long long a1 = (unsigned long long)p1;
    unsigned long long a2 = (unsigned long long)p2;
    unsigned long long a3 = (unsigned long long)p3;
    asm volatile(
        "global_load_dwordx2 %0, %4, off sc0 sc1\n\t"
        "global_load_dwordx2 %1, %5, off sc0 sc1\n\t"
        "global_load_dwordx2 %2, %6, off sc0 sc1\n\t"
        "global_load_dwordx2 %3, %7, off sc0 sc1\n\t"
        "s_waitcnt vmcnt(0)"
        : "=v"(w0), "=v"(w1), "=v"(w2), "=v"(w3)
        : "v"(a0), "v"(a1), "v"(a2), "v"(a3) : "memory");
}
// issue WITHOUT waiting (drain later with a separate vmcnt(0))
__device__ __forceinline__ void scload64x4_issue(
    const u64* p0, const u64* p1, const u64* p2, const u64* p3,
    u64& w0, u64& w1, u64& w2, u64& w3)
{
    unsigned long long a0 = (unsigned long long)p0;
    unsigned long long a1 = (unsigned long long)p1;
    unsigned long long a2 = (unsigned long long)p2;
    unsigned long long a3 = (unsigned long long)p3;
    asm volatile(
        "global_load_dwordx2 %0, %4, off sc0 sc1\n\t"
        "global_load_dwordx2 %1, %5, off sc0 sc1\n\t"
        "global_load_dwordx2 %2, %6, off sc0 sc1\n\t"
        "global_load_dwordx2 %3, %7, off sc0 sc1"
        : "=v"(w0), "=v"(w1), "=v"(w2), "=v"(w3)
        : "v"(a0), "v"(a1), "v"(a2), "v"(a3) : "memory");
}

#define PAIR_DOT(wa0, wb0, wa1, wb1, h4)                                  \
    do {                                                                   \
        a0 = __builtin_amdgcn_fdot2(h2_((wa0).x), h2_((h4).x), a0, false); \
        a0 = __builtin_amdgcn_fdot2(h2_((wa0).y), h2_((h4).y), a0, false); \
        a1 = __builtin_amdgcn_fdot2(h2_((wa0).z), h2_((h4).x), a1, false); \
        a1 = __builtin_amdgcn_fdot2(h2_((wa0).w), h2_((h4).y), a1, false); \
        a2 = __builtin_amdgcn_fdot2(h2_((wb0).x), h2_((h4).x), a2, false); \
        a2 = __builtin_amdgcn_fdot2(h2_((wb0).y), h2_((h4).y), a2, false); \
        a3 = __builtin_amdgcn_fdot2(h2_((wb0).z), h2_((h4).x), a3, false); \
        a3 = __builtin_amdgcn_fdot2(h2_((wb0).w), h2_((h4).y), a3, false); \
        a0 = __builtin_amdgcn_fdot2(h2_((wa1).x), h2_((h4).z), a0, false); \
        a0 = __builtin_amdgcn_fdot2(h2_((wa1).y), h2_((h4).w), a0, false); \
        a1 = __builtin_amdgcn_fdot2(h2_((wa1).z), h2_((h4).z), a1, false); \
        a1 = __builtin_amdgcn_fdot2(h2_((wa1).w), h2_((h4).w), a1, false); \
        a2 = __builtin_amdgcn_fdot2(h2_((wb1).x), h2_((h4).z), a2, false); \
        a2 = __builtin_amdgcn_fdot2(h2_((wb1).y), h2_((h4).w), a2, false); \
        a3 = __builtin_amdgcn_fdot2(h2_((wb1).z), h2_((h4).z), a3, false); \
        a3 = __builtin_amdgcn_fdot2(h2_((wb1).w), h2_((h4).w), a3, false); \
    } while (0)

// dot phase, R23 order: REG -> LDS -> STREAM.  The stream section (with its
// vmem waits) comes LAST so tail atomics from the previous step have the
// whole REG+LDS span to drain before any vmcnt wait occurs.
#define DOT_PHASE()                                                        \
    do {                                                                   \
        _Pragma("unroll")                                                  \
        for (int p = 0; p < PREG; p++) {                                   \
            uint4 h4 = hp4[hb + p];                                        \
            PAIR_DOT(wreg[4 * p], wreg[4 * p + 1],                         \
                     wreg[4 * p + 2], wreg[4 * p + 3], h4);                \
        }                                                                  \
        _Pragma("unroll")                                                  \
        for (int p = 0; p < PLDS; p++) {                                   \
            uint4 wa0 = Wlh[(p * 4 + 0) * 512 + tid];                      \
            uint4 wb0 = Wlh[(p * 4 + 1) * 512 + tid];                      \
            uint4 wa1 = Wlh[(p * 4 + 2) * 512 + tid];                      \
            uint4 wb1 = Wlh[(p * 4 + 3) * 512 + tid];                      \
            uint4 h4  = hp4[hb + PREG + p];                                \
            PAIR_DOT(wa0, wb0, wa1, wb1, h4);                              \
        }                                                                  \
        _Pragma("unroll 2")                                                \
        for (int p = 0; p < PSTR; p++) {                                   \
            uint4 wa0 = Ws[(p * 4 + 0) * 512 + tid];                       \
            uint4 wb0 = Ws[(p * 4 + 1) * 512 + tid];                       \
            uint4 wa1 = Ws[(p * 4 + 2) * 512 + tid];                       \
            uint4 wb1 = Ws[(p * 4 + 3) * 512 + tid];                       \
            uint4 h4  = hp4[hb + PREG + PLDS + p];                         \
            PAIR_DOT(wa0, wb0, wa1, wb1, h4);                              \
        }                                                                  \
    } while (0)

// ---------------------------------------------------------------------------
__global__ __launch_bounds__(256) void embed_kernel(
    const int* __restrict__ actions, const float* __restrict__ emb_table,
    float* __restrict__ X, float* __restrict__ dact)
{
    int row = blockIdx.x;
    int t = row & (TT - 1);
    int id = (t == 0) ? 0 : actions[row - 1];
    X[(int64_t)row * HT + threadIdx.x] = emb_table[(int64_t)id * HT + threadIdx.x];
    if (threadIdx.x == 0) dact[row] = (float)actions[row];
}

// ---------------------------------------------------------------------------
// Repack 3 weight matrices to the R10 fp16 layout:
// slot 0 = Whh layer0 (role A), slot 1 = Whh layer1 (role C),
// slot 2 = Wih layer1 (role B).
__global__ __launch_bounds__(256) void repack_w_kernel(
    const float* __restrict__ Whh, const float* __restrict__ Wih,
    uint4* __restrict__ Wpkh)
{
    int idx = blockIdx.x * 256 + threadIdx.x;   // 0..98303
    int g   = idx & 32767;
    int l   = idx >> 15;                        // 0..2
    int tid = g & 511;
    int ab  = (g >> 9) & 1;
    int u   = (g >> 10) & 31;
    int s = tid >> 8, q = tid & 255;
    int r0 = 4 * q + 2 * ab;
    int k  = 128 * s + 4 * u;
    const float* base = (l == 0) ? Whh
                      : (l == 1) ? Whh + (int64_t)GATES * HT
                                 : Wih + (int64_t)GATES * HT;
    const float4 a = *(const float4*)(base + (int64_t)r0 * HT + k);
    const float4 b = *(const float4*)(base + (int64_t)(r0 + 1) * HT + k);
    half2_t p0 = {(half_t)a.x, (half_t)a.y};
    half2_t p1 = {(half_t)a.z, (half_t)a.w};
    half2_t p2 = {(half_t)b.x, (half_t)b.y};
    half2_t p3 = {(half_t)b.z, (half_t)b.w};
    uint4 o;
    o.x = __builtin_bit_cast(unsigned int, p0);
    o.y = __builtin_bit_cast(unsigned int, p1);
    o.z = __builtin_bit_cast(unsigned int, p2);
    o.w = __builtin_bit_cast(unsigned int, p3);
    Wpkh[idx] = o;
}

// ---------------------------------------------------------------------------
// Zero the h0 exchange buffer + Ag1 stamped ring + progress counters.
__global__ __launch_bounds__(256) void hxzero_kernel(
    uint4* __restrict__ HX4, u64* __restrict__ AGU,
    unsigned int* __restrict__ CCTR)
{
    int i = blockIdx.x * 256 + threadIdx.x;     // grid 8192 -> 2M
    HX4[i] = make_uint4(0u, 0u, 0u, 0u);
    if (i < AGDEPTH * 64 * 1024) AGU[i] = 0ull;
    if (i < 64) CCTR[i] = 0u;
}

// ---------------------------------------------------------------------------
// MFMA fp16 GEMM: C = act( A @ op(B) + bias1 + bias2 ), fp32 in/out.
template<bool TRANS_B, int ACT>
__global__ __launch_bounds__(256) void mfma_gemm_kernel(
    const float* __restrict__ A, const float* __restrict__ Bm,
    float* __restrict__ C,
    int K, int lda, int ldb, int ldc,
    int64_t sA, int64_t sB, int64_t sC,
    const float* __restrict__ bias1, const float* __restrict__ bias2)
{
    constexpr int BM = 128, BN = 128, BK = 32;
    constexpr int LDT = BK + 8;
    __shared__ __align__(16) half_t Asl[BM * LDT];
    __shared__ __align__(16) half_t Bsl[BN * LDT];

    const int tid  = threadIdx.x;
    const int wave = tid >> 6;
    const int lane = tid & 63;
    const int wm = (wave & 1) * 64;
    const int wn = (wave >> 1) * 64;
    const int m0 = blockIdx.y * BM;
    const int n0 = blockIdx.x * BN;
    A  += (int64_t)blockIdx.z * sA;
    Bm += (int64_t)blockIdx.z * sB;
    C  += (int64_t)blockIdx.z * sC;

    const int fm = lane & 15;
    const int qd = lane >> 4;

    f32x4 acc[4][4] = {};

    for (int k0 = 0; k0 < K; k0 += BK) {
        #pragma unroll
        for (int i = 0; i < 4; i++) {
            int idx = tid + i * 256;
            int r  = idx >> 3;
            int kq = idx & 7;
            float4 v = *(const float4*)(A + (int64_t)(m0 + r) * lda + k0 + kq * 4);
            half_t* d = &Asl[r * LDT + kq * 4];
            d[0] = (half_t)v.x; d[1] = (half_t)v.y;
            d[2] = (half_t)v.z; d[3] = (half_t)v.w;
        }
        if (TRANS_B) {
            #pragma unroll
            for (int i = 0; i < 4; i++) {
                int idx = tid + i * 256;
                int r  = idx >> 3;
                int kq = idx & 7;
                float4 v = *(const float4*)(Bm + (int64_t)(n0 + r) * ldb + k0 + kq * 4);
                half_t* d = &Bsl[r * LDT + kq * 4];
                d[0] = (half_t)v.x; d[1] = (half_t)v.y;
                d[2] = (half_t)v.z; d[3] = (half_t)v.w;
            }
        } else {
            #pragma unroll
            for (int i = 0; i < 4; i++) {
                int idx = tid + i * 256;
                int kk = idx >> 5;
                int nq = idx & 31;
                float4 v = *(const float4*)(Bm + (int64_t)(k0 + kk) * ldb + n0 + nq * 4);
                Bsl[(nq * 4 + 0) * LDT + kk] = (half_t)v.x;
                Bsl[(nq * 4 + 1) * LDT + kk] = (half_t)v.y;
                Bsl[(nq * 4 + 2) * LDT + kk] = (half_t)v.z;
                Bsl[(nq * 4 + 3) * LDT + kk] = (half_t)v.w;
            }
        }
        __syncthreads();

        typedef _Float16 f16x8 __attribute__((ext_vector_type(8)));
        f16x8 af[4], bf[4];
        #pragma unroll
        for (int t = 0; t < 4; t++)
            af[t] = *(const f16x8*)&Asl[(wm + t * 16 + fm) * LDT + qd * 8];
        #pragma unroll
        for (int t = 0; t < 4; t++)
            bf[t] = *(const f16x8*)&Bsl[(wn + t * 16 + fm) * LDT + qd * 8];
        #pragma unroll
        for (int mt = 0; mt < 4; mt++)
            #pragma unroll
            for (int nt = 0; nt < 4; nt++)
                acc[mt][nt] = __builtin_amdgcn_mfma_f32_16x16x32_f16(
                                  af[mt], bf[nt], acc[mt][nt], 0, 0, 0);
        __syncthreads();
    }

    #pragma unroll
    for (int nt = 0; nt < 4; nt++) {
        int n = n0 + wn + nt * 16 + fm;
        float bv = 0.0f;
        if (bias1) bv += bias1[n];
        if (bias2) bv += bias2[n];
        #pragma unroll
        for (int mt = 0; mt < 4; mt++) {
            #pragma unroll
            for (int r = 0; r < 4; r++) {
                int m = m0 + wm + mt * 16 + qd * 4 + r;
                float v = acc[mt][nt][r] + bv;
                if (ACT == 1) v = tanhf(v);
                C[(int64_t)m * ldc + n] = v;
            }
        }
    }
}

// ---------------------------------------------------------------------------
// Generic fp32 tiled GEMM (output chain precision).
template<bool TRANS_B, int ACT>
__global__ __launch_bounds__(256) void gemm128_kernel(
    const float* __restrict__ A, const float* __restrict__ Bm,
    float* __restrict__ C,
    int K, int lda, int ldb, int ldc,
    int64_t sA, int64_t sB, int64_t sC,
    const float* __restrict__ bias1, const float* __restrict__ bias2)
{
    constexpr int BM = 128, BN = 128, BK = 16;
    __shared__ __align__(16) float As[BK][BM + 4];
    __shared__ __align__(16) float Bs[BK][BN + 4];

    const int tid = threadIdx.x;
    const int m0 = blockIdx.y * BM;
    const int n0 = blockIdx.x * BN;
    A  += (int64_t)blockIdx.z * sA;
    Bm += (int64_t)blockIdx.z * sB;
    C  += (int64_t)blockIdx.z * sC;

    const int tm = tid & 15;
    const int tn = tid >> 4;

    float acc[8][8] = {};

    for (int k0 = 0; k0 < K; k0 += BK) {
        #pragma unroll
        for (int i = 0; i < 2; i++) {
            int idx = tid + i * 256;
            int ar = idx >> 2;
            int ak = (idx & 3) * 4;
            const float4 v = *(const float4*)(A + (int64_t)(m0 + ar) * lda + k0 + ak);
            As[ak + 0][ar] = v.x; As[ak + 1][ar] = v.y;
            As[ak + 2][ar] = v.z; As[ak + 3][ar] = v.w;
        }
        if (TRANS_B) {
            #pragma unroll
            for (int i = 0; i < 2; i++) {
                int idx = tid + i * 256;
                int br = idx >> 2;
                int bk = (idx & 3) * 4;
                const float4 v = *(const float4*)(Bm + (int64_t)(n0 + br) * ldb + k0 + bk);
                Bs[bk + 0][br] = v.x; Bs[bk + 1][br] = v.y;
                Bs[bk + 2][br] = v.z; Bs[bk + 3][br] = v.w;
            }
        } else {
            #pragma unroll
            for (int i = 0; i < 2; i++) {
                int idx = tid + i * 256;
                int bk = idx >> 5;
                int bn = (idx & 31) * 4;
                const float4 v = *(const float4*)(Bm + (int64_t)(k0 + bk) * ldb + n0 + bn);
                *(float4*)&Bs[bk][bn] = v;
            }
        }
        __syncthreads();

        #pragma unroll
        for (int k = 0; k < BK; k++) {
            float a[8], b[8];
            *(float4*)&a[0] = *(const float4*)&As[k][tm * 8];
            *(float4*)&a[4] = *(const float4*)&As[k][tm * 8 + 4];
            *(float4*)&b[0] = *(const float4*)&Bs[k][tn * 8];
            *(float4*)&b[4] = *(const float4*)&Bs[k][tn * 8 + 4];
            #pragma unroll
            for (int i = 0; i < 8; i++)
                #pragma unroll
                for (int j = 0; j < 8; j++)
                    acc[i][j] += a[i] * b[j];
        }
        __syncthreads();
    }

    float bv[8];
    #pragma unroll
    for (int j = 0; j < 8; j++) {
        int n = n0 + tn * 8 + j;
        float b = 0.0f;
        if (bias1) b += bias1[n];
        if (bias2) b += bias2[n];
        bv[j] = b;
    }
    #pragma unroll
    for (int i = 0; i < 8; i++) {
        int64_t m = m0 + tm * 8 + i;
        float o[8];
        #pragma unroll
        for (int j = 0; j < 8; j++) {
            float v = acc[i][j] + bv[j];
            if (ACT == 1) v = tanhf(v);
            o[j] = v;
        }
        *(float4*)(C + m * ldc + n0 + tn * 8)     = make_float4(o[0], o[1], o[2], o[3]);
        *(float4*)(C + m * ldc + n0 + tn * 8 + 4) = make_float4(o[4], o[5], o[6], o[7]);
    }
}

// ---------------------------------------------------------------------------
// Fused pipelined recurrence.  grid = 192 blocks (role = bid>>6, b = bid&63),
// 512 threads, 1 block/CU -> all co-resident.  Dataflow A -> B -> C only.
__global__ __launch_bounds__(512)
__attribute__((amdgpu_waves_per_eu(2, 2)))
void fused_rec_kernel(
    const float* __restrict__ Ag0,
    const uint4* __restrict__ Wpk,
    const float* __restrict__ h0l,
    const float* __restrict__ c0l,
    const float* __restrict__ bih,
    const float* __restrict__ bhh,
    float* __restrict__ cat,
    unsigned int* __restrict__ HX,     // [B*T*H] stamped h0 (write-once)
    u64* __restrict__ AGU,             // [AGDEPTH][64][1024] stamped Ag1 ring
    unsigned int* __restrict__ CCTR)   // [64] C progress counters
{
    const int bid  = blockIdx.x;
    const int role = bid >> 6;          // 0=A, 1=B, 2=C
    const int b    = bid & 63;
    const int tid  = threadIdx.x;
    const int s    = tid >> 8;
    const int q    = tid & 255;

    __shared__ __align__(16) uint4          Wlh[ULDS * 2 * 512];   // 128 KB
    __shared__ __align__(16) float          gsh2[2 * GATES];       // 8 KB
    __shared__ __align__(16) float          agsh[2][GATES];        // 8 KB (role C)
    __shared__ __align__(16) unsigned short hsh[HT];               // 512 B

    const uint4* Wb = Wpk + (role == 0 ? 0 : (role == 1 ? 2 : 1)) * 32768;

    uint4 wreg[2 * UREG];
    #pragma unroll
    for (int u = 0; u < UREG; u++) {
        wreg[2 * u]     = Wb[(u * 2 + 0) * 512 + tid];
        wreg[2 * u + 1] = Wb[(u * 2 + 1) * 512 + tid];
    }
    #pragma unroll
    for (int v = 0; v < ULDS; v++) {
        Wlh[(v * 2 + 0) * 512 + tid] = Wb[((UREG + v) * 2 + 0) * 512 + tid];
        Wlh[(v * 2 + 1) * 512 + tid] = Wb[((UREG + v) * 2 + 1) * 512 + tid];
    }
    const uint4* __restrict__ Ws = Wb + (UREG + ULDS) * 2 * 512;
    const uint4* hp4 = (const uint4*)hsh;
    const int hb = 16 * s;

    if (role == 0) {
        // ---------------- Role A: layer-0 recurrence (R10) + publish ------
        if (tid < HT) {
            half_t hv = (half_t)h0l[b * HT + tid];
            hsh[tid] = __builtin_bit_cast(unsigned short, hv);
        }
        float c = (tid < HT) ? c0l[b * HT + tid] : 0.0f;
        const float* AgB = Ag0 + (int64_t)b * TT * GATES;
        unsigned int* HXb = HX + (int64_t)b * TT * HT;
        __syncthreads();

        #pragma unroll 1
        for (int st = 0; st < TT; st++) {
            float4 aval = make_float4(0.f, 0.f, 0.f, 0.f);
            if (s == 0) aval = *(const float4*)(AgB + (int64_t)st * GATES + 4 * q);
            float a0 = 0.f, a1 = 0.f, a2 = 0.f, a3 = 0.f;
            DOT_PHASE();
            a0 += aval.x; a1 += aval.y; a2 += aval.z; a3 += aval.w;
            *(float4*)&gsh2[s * GATES + 4 * q] = make_float4(a0, a1, a2, a3);
            WG_BARRIER();
            if (tid < HT) {
                float gi = gsh2[tid]          + gsh2[GATES + tid];
                float gf = gsh2[HT + tid]     + gsh2[GATES + HT + tid];
                float gg = gsh2[2 * HT + tid] + gsh2[GATES + 2 * HT + tid];
                float go = gsh2[3 * HT + tid] + gsh2[GATES + 3 * HT + tid];
                c = fast_sig(gf) * c + fast_sig(gi) * fast_tanh(gg);
                float h = fast_sig(go) * fast_tanh(c);
                half_t hh = (half_t)h;
                unsigned short hb16 = __builtin_bit_cast(unsigned short, hh);
                hsh[tid] = hb16;
                atomicExch(HXb + (int64_t)st * HT + tid,
                           ((unsigned)(st + 1) << 16) | (unsigned)hb16);
            }
            WG_BARRIER();
        }
    } else if (role == 1) {
        // ---------------- Role B: layer-1 input matvec --------------------
        // biases live on the PUBLISHING waves (4-7); polling waves (0-3)
        // never issue atomics so their vmcnt(0) polls stay clean.
        float bi_ = 0.f, bf_ = 0.f, bg_ = 0.f, bo_ = 0.f;
        if (tid >= 256) {
            int i = tid - 256;
            bi_ = bih[GATES + i]          + bhh[GATES + i];
            bf_ = bih[GATES + HT + i]     + bhh[GATES + HT + i];
            bg_ = bih[GATES + 2 * HT + i] + bhh[GATES + 2 * HT + i];
            bo_ = bih[GATES + 3 * HT + i] + bhh[GATES + 3 * HT + i];
        }
        const unsigned int* HXb = HX + (int64_t)b * TT * HT;
        __syncthreads();

        #pragma unroll 1
        for (int st = 0; st < TT; st++) {
            // ring back-pressure: ensure C consumed slot before reuse
            if ((st & 3) == 0 && st >= AGDEPTH && tid == 0) {
                unsigned cc = scload(&CCTR[b]);
                while (cc < (unsigned)(st - (AGDEPTH - 4))) {
                    __builtin_amdgcn_s_sleep(2);
                    cc = scload(&CCTR[b]);
                }
            }
            // poll h0_t (write-once stamped words) with sleep backoff
            if (tid < HT) {
                const unsigned int* src = HXb + (int64_t)st * HT + tid;
                unsigned int w = scload(src);
                while ((w >> 16) != (unsigned)(st + 1)) {
                    __builtin_amdgcn_s_sleep(1);
                    w = scload(src);
                }
                hsh[tid] = (unsigned short)(w & 0xffffu);
            }
            WG_BARRIER();
            float a0 = 0.f, a1 = 0.f, a2 = 0.f, a3 = 0.f;
            DOT_PHASE();
            *(float4*)&gsh2[s * GATES + 4 * q] = make_float4(a0, a1, a2, a3);
            WG_BARRIER();
            // combine + publish from waves 4-7 (stamp-in-word u64 atomics,
            // fire-and-forget; drain hidden under next dot's REG+LDS span)
            if (tid >= 256) {
                int i = tid - 256;
                u64 hi = ((u64)(st + 1)) << 32;
                u64* dst = AGU + (int64_t)((st & (AGDEPTH - 1)) * 64 + b) * 1024;
                float v0 = gsh2[i]          + gsh2[GATES + i]          + bi_;
                float v1 = gsh2[HT + i]     + gsh2[GATES + HT + i]     + bf_;
                float v2 = gsh2[2 * HT + i] + gsh2[GATES + 2 * HT + i] + bg_;
                float v3 = gsh2[3 * HT + i] + gsh2[GATES + 3 * HT + i] + bo_;
                atomicExch(&dst[i],          hi | (u64)__float_as_uint(v0));
                atomicExch(&dst[HT + i],     hi | (u64)__float_as_uint(v1));
                atomicExch(&dst[2 * HT + i], hi | (u64)__float_as_uint(v2));
                atomicExch(&dst[3 * HT + i], hi | (u64)__float_as_uint(v3));
            }
            // no third barrier: next poll writes hsh (ordered by barrier #1)
        }
    } else {
        // ---------------- Role C: layer-1 recurrence ----------------------
        if (tid < HT) {
            half_t hv = (half_t)h0l[BB * HT + b * HT + tid];
            hsh[tid] = __builtin_bit_cast(unsigned short, hv);
        }
        float c = (tid < HT) ? c0l[BB * HT + b * HT + tid] : 0.0f;
        __syncthreads();
        // preload Ag1(0) into agsh[0] (waves 4-7, batch-validated, blocking)
        if (tid >= 256) {
            int i = tid - 256;
            const u64* src = AGU + (int64_t)b * 1024;
            u64 w0, w1, w2, w3;
            scload64x4(src + i, src + i + 256, src + i + 512, src + i + 768,
                       w0, w1, w2, w3);
            while ((unsigned)(w0 >> 32) != 1u) { __builtin_amdgcn_s_sleep(1); w0 = scload64(src + i); }
            while ((unsigned)(w1 >> 32) != 1u) { __builtin_amdgcn_s_sleep(1); w1 = scload64(src + i + 256); }
            while ((unsigned)(w2 >> 32) != 1u) { __builtin_amdgcn_s_sleep(1); w2 = scload64(src + i + 512); }
            while ((unsigned)(w3 >> 32) != 1u) { __builtin_amdgcn_s_sleep(1); w3 = scload64(src + i + 768); }
            agsh[0][i]       = __uint_as_float((unsigned)w0);
            agsh[0][i + 256] = __uint_as_float((unsigned)w1);
            agsh[0][i + 512] = __uint_as_float((unsigned)w2);
            agsh[0][i + 768] = __uint_as_float((unsigned)w3);
        }
        WG_BARRIER();

        #pragma unroll 1
        for (int st = 0; st < TT; st++) {
            // issue Ag1(st+1) loads BEFORE the dot (drain after barrier):
            // the ~1-RTT latency hides entirely under the ~3470cy dot.
            u64 pw0 = 0, pw1 = 0, pw2 = 0, pw3 = 0;
            if (tid >= 256 && st + 1 < TT) {
                int i = tid - 256;
                int sl = (st + 1) & (AGDEPTH - 1);
                const u64* src = AGU + (int64_t)(sl * 64 + b) * 1024;
                scload64x4_issue(src + i, src + i + 256, src + i + 512,
                                 src + i + 768, pw0, pw1, pw2, pw3);
            }
            float a0 = 0.f, a1 = 0.f, a2 = 0.f, a3 = 0.f;
            DOT_PHASE();
            *(f32x4*)&gsh2[s * GATES + 4 * q] = f32x4{a0, a1, a2, a3};
            WG_BARRIER();
            if (tid < HT) {
                const float* ag = agsh[st & 1];
                float gi = gsh2[tid]          + gsh2[GATES + tid]          + ag[tid];
                float gf = gsh2[HT + tid]     + gsh2[GATES + HT + tid]     + ag[HT + tid];
                float gg = gsh2[2 * HT + tid] + gsh2[GATES + 2 * HT + tid] + ag[2 * HT + tid];
                float go = gsh2[3 * HT + tid] + gsh2[GATES + 3 * HT + tid] + ag[3 * HT + tid];
                c = fast_sig(gf) * c + fast_sig(gi) * fast_tanh(gg);
                float h = fast_sig(go) * fast_tanh(c);
                hsh[tid] = __builtin_bit_cast(unsigned short, (half_t)h);
                cat[((int64_t)b * TT + st) * (2 * HT) + tid] = h;
            } else {
                if ((st & 3) == 3 && tid == 256)
                    atomicExch(&CCTR[b], (unsigned)(st + 1));
                if (st + 1 < TT) {
                    int i = tid - 256;
                    int sl = (st + 1) & (AGDEPTH - 1);
                    unsigned expect = (unsigned)(st + 2);
                    const u64* src = AGU + (int64_t)(sl * 64 + b) * 1024;
                    asm volatile("s_waitcnt vmcnt(0)" ::: "memory");
                    while ((unsigned)(pw0 >> 32) != expect) { __builtin_amdgcn_s_sleep(1); pw0 = scload64(src + i); }
                    while ((unsigned)(pw1 >> 32) != expect) { __builtin_amdgcn_s_sleep(1); pw1 = scload64(src + i + 256); }
                    while ((unsigned)(pw2 >> 32) != expect) { __builtin_amdgcn_s_sleep(1); pw2 = scload64(src + i + 512); }
                    while ((unsigned)(pw3 >> 32) != expect) { __builtin_amdgcn_s_sleep(1); pw3 = scload64(src + i + 768); }
                    float* d = agsh[(st + 1) & 1];
                    d[i]       = __uint_as_float((unsigned)pw0);
                    d[i + 256] = __uint_as_float((unsigned)pw1);
                    d[i + 512] = __uint_as_float((unsigned)pw2);
                    d[i + 768] = __uint_as_float((unsigned)pw3);
                }
            }
            WG_BARRIER();
        }
    }
}

// ---------------------------------------------------------------------------
__global__ __launch_bounds__(256) void softmax512_kernel(float* __restrict__ S)
{
    int row = blockIdx.x * 4 + (threadIdx.x >> 6);
    int lane = threadIdx.x & 63;
    float* p = S + (int64_t)row * 512 + lane * 8;
    float4 v0 = *(float4*)p;
    float4 v1 = *(float4*)(p + 4);
    float m = fmaxf(fmaxf(fmaxf(v0.x, v0.y), fmaxf(v0.z, v0.w)),
                    fmaxf(fmaxf(v1.x, v1.y), fmaxf(v1.z, v1.w)));
    #pragma unroll
    for (int off = 32; off; off >>= 1) m = fmaxf(m, __shfl_xor(m, off));
    v0.x = __expf(v0.x - m); v0.y = __expf(v0.y - m);
    v0.z = __expf(v0.z - m); v0.w = __expf(v0.w - m);
    v1.x = __expf(v1.x - m); v1.y = __expf(v1.y - m);
    v1.z = __expf(v1.z - m); v1.w = __expf(v1.w - m);
    float s = v0.x + v0.y + v0.z + v0.w + v1.x + v1.y + v1.z + v1.w;
    #pragma unroll
    for (int off = 32; off; off >>= 1) s += __shfl_xor(s, off);
    float inv = 1.0f / s;
    v0.x *= inv; v0.y *= inv; v0.z *= inv; v0.w *= inv;
    v1.x *= inv; v1.y *= inv; v1.z *= inv; v1.w *= inv;
    *(float4*)p = v0;
    *(float4*)(p + 4) = v1;
}

__global__ __launch_bounds__(256) void values_kernel(
    const float* __restrict__ Q, const float* __restrict__ L, float* __restrict__ V)
{
    int row = blockIdx.x * 4 + (threadIdx.x >> 6);
    int lane = threadIdx.x & 63;
    float2 q = *(const float2*)(Q + (int64_t)row * OO + lane * 2);
    float2 l = *(const float2*)(L + (int64_t)row * OO + lane * 2);
    float s = q.x * l.x + q.y * l.y;
    #pragma unroll
    for (int off = 32; off; off >>= 1) s += __shfl_xor(s, off);
    if (lane == 0) V[row] = s;
}

// ---------------------------------------------------------------------------
extern "C" void kernel_launch(void* const* d_in, const int* in_sizes, int n_in,
                              void* d_out, int out_size, void* d_ws, size_t ws_size,
                              hipStream_t stream)
{
    const float* enc      = (const float*)d_in[0];
    const float* h0       = (const float*)d_in[1];
    const float* c0       = (const float*)d_in[2];
    const int*   actions  = (const int*)  d_in[3];
    const float* emb_t    = (const float*)d_in[4];
    const float* Wih      = (const float*)d_in[5];
    const float* Whh      = (const float*)d_in[6];
    const float* bih      = (const float*)d_in[7];
    const float* bhh      = (const float*)d_in[8];
    const float* W_attn   = (const float*)d_in[9];
    const float* b_attn   = (const float*)d_in[10];
    const float* W_concat = (const float*)d_in[11];
    const float* b_concat = (const float*)d_in[12];
    const float* W_out    = (const float*)d_in[13];
    const float* W_critic = (const float*)d_in[14];
    const float* b_critic = (const float*)d_in[15];
    (void)in_sizes; (void)n_in; (void)out_size; (void)ws_size;

    const int M = BB * TT;                 // 32768

    float* out    = (float*)d_out;
    float* dact   = out;
    float* logits = out + M;
    float* values = out + M + (int64_t)M * OO;

    float* ws    = (float*)d_ws;
    float* gates = ws;                       // Ag0, 128 MB
    float* xbuf  = ws + 33554432;            // emb -> (zeroed) -> HX -> dec
    float* cat   = ws + 41943040;            // [M,512]: h1 | ctx
    float* keysR = ws + 58720256;
    float* keys  = keysR;
    uint4* Wpkh  = (uint4*)keysR;            // 1.5 MB; dead before keys
    u64*   AGU   = (u64*)(ws + 59500000);    // 8 MB stamped ring (dead-keys region)
    unsigned int* CCTR = (unsigned int*)(ws + 61600000);
    unsigned int* HX   = (unsigned int*)xbuf;
    float* scores = gates;
    float* qv     = gates;
    float* dec    = xbuf;

    // 1) embedding -> xbuf, + decoder_action
    hipLaunchKernelGGL(embed_kernel, dim3(M), dim3(256), 0, stream,
                       actions, emb_t, xbuf, dact);
    // 2) repack Whh0/Whh1/Wih1 to fp16 R10 layout
    hipLaunchKernelGGL(repack_w_kernel, dim3(384), dim3(256), 0, stream,
                       Whh, Wih, Wpkh);
    // 3) layer-0 input GEMM: gates = emb @ Wih0^T + bih0 + bhh0
    hipLaunchKernelGGL((mfma_gemm_kernel<true, 0>), dim3(8, 256, 1), dim3(256), 0, stream,
                       xbuf, Wih, gates, HT, HT, HT, GATES,
                       (int64_t)0, (int64_t)0, (int64_t)0, bih, bhh);
    // 4) zero h0-exchange buffer (emb consumed) + stamped ring + counters
    hipLaunchKernelGGL(hxzero_kernel, dim3(8192), dim3(256), 0, stream,
                       (uint4*)HX, AGU, CCTR);
    // 5) fused pipelined recurrence: L0 rec || L1 input || L1 rec
    hipLaunchKernelGGL(fused_rec_kernel, dim3(192), dim3(512), 0, stream,
                       gates, Wpkh, h0, c0, bih, bhh, cat, HX, AGU, CCTR);
    // 6) keys = enc @ W_attn^T + b_attn (MFMA fp16)
    hipLaunchKernelGGL((mfma_gemm_kernel<true, 0>), dim3(2, 256, 1), dim3(256), 0, stream,
                       enc, W_attn, keys, HT, HT, HT, HT,
                       (int64_t)0, (int64_t)0, (int64_t)0, b_attn, (const float*)nullptr);
    // 7) scores[b] = out[b] @ keys[b]^T  (MFMA fp16, fp32 accumulate)
    hipLaunchKernelGGL((mfma_gemm_kernel<true, 0>), dim3(4, 4, BB), dim3(256), 0, stream,
                       cat, keys, scores, HT, 2 * HT, HT, TT,
                       (int64_t)TT * 2 * HT, (int64_t)TT * HT, (int64_t)TT * TT,
                       (const float*)nullptr, (const float*)nullptr);
    // 8) softmax
    hipLaunchKernelGGL(softmax512_kernel, dim3(M / 4), dim3(256), 0, stream, scores);
    // 9) ctx[b] = P[b] @ enc[b] -> cat[:,256:]  (MFMA fp16)
    hipLaunchKernelGGL((mfma_gemm_kernel<false, 0>), dim3(2, 4, BB), dim3(256), 0, stream,
                       scores, enc, cat + HT, TT, TT, HT, 2 * HT,
                       (int64_t)TT * TT, (int64_t)TT * HT, (int64_t)TT * 2 * HT,
                       (const float*)nullptr, (const float*)nullptr);
    // 10) dec = tanh(cat @ W_concat^T + b_concat)
    hipLaunchKernelGGL((mfma_gemm_kernel<true, 1>), dim3(2, 256, 1), dim3(256), 0, stream,
                       cat, W_concat, dec, 2 * HT, 2 * HT, 2 * HT, HT,
                       (int64_t)0, (int64_t)0, (int64_t)0, b_concat, (const float*)nullptr);
    // 11) logits = dec @ W_out^T  (fp32 — output path)
    hipLaunchKernelGGL((gemm128_kernel<true, 0>), dim3(1, 256, 1), dim3(256), 0, stream,
                       dec, W_out, logits, HT, HT, HT, OO,
                       (int64_t)0, (int64_t)0, (int64_t)0,
                       (const float*)nullptr, (const float*)nullptr);
    // 12) qv = logits @ W_critic^T + b_critic  (fp32 — output path)
    hipLaunchKernelGGL((gemm128_kernel<true, 0>), dim3(1, 256, 1), dim3(256), 0, stream,
                       logits, W_critic, qv, OO, OO, OO, OO,
                       (int64_t)0, (int64_t)0, (int64_t)0, b_critic, (const float*)nullptr);
    // 13) values
    hipLaunchKernelGGL(values_kernel, dim3(M / 4), dim3(256), 0, stream,
                       qv, logits, values);
}